// Round 1
// baseline (909.872 us; speedup 1.0000x reference)
//
#include <hip/hip_runtime.h>

#define D 768
#define D3 2304

typedef __bf16 bf16x8 __attribute__((ext_vector_type(8)));
typedef float f32x4 __attribute__((ext_vector_type(4)));

__device__ __forceinline__ float b2f(unsigned short u) {
    unsigned int i = ((unsigned int)u) << 16;
    return __builtin_bit_cast(float, i);
}
__device__ __forceinline__ unsigned short f2b(float f) {
    unsigned int i = __builtin_bit_cast(unsigned int, f);
    i += 0x7FFFu + ((i >> 16) & 1u);   // RNE
    return (unsigned short)(i >> 16);
}
__device__ __forceinline__ float sigm(float x) { return 1.0f / (1.0f + __expf(-x)); }

// async global->LDS, 16B per lane. LDS dest is wave-uniform base + lane*16.
typedef __attribute__((address_space(1))) const unsigned int* as1p;
typedef __attribute__((address_space(3))) unsigned int* as3p;
__device__ __forceinline__ void glds16(const unsigned short* g, unsigned short* l)
{
    __builtin_amdgcn_global_load_lds((as1p)g, (as3p)l, 16, 0, 0);
}

// fp32 -> bf16 cast, 4 elems/thread
__global__ void k_cast(const float* __restrict__ in, unsigned short* __restrict__ out, int n)
{
    int i4 = (blockIdx.x * blockDim.x + threadIdx.x) * 4;
    if (i4 >= n) return;
    float4 v = *(const float4*)(in + i4);
    ushort4 u;
    u.x = f2b(v.x); u.y = f2b(v.y); u.z = f2b(v.z); u.w = f2b(v.w);
    *(ushort4*)(out + i4) = u;
}

// ---------------------------------------------------------------------------
// NT GEMM, m97 structure: C[M,N] = act(A[M,K] @ B[N,K]^T + bias[N])
// 128x128 tile, BK=32, 4 waves (2x2), 4x4 16x16x32 MFMA frags per wave.
// Staging via global_load_lds width=16: wave w fills 1KB chunks {2w,2w+1}
// of As and Bs; per lane: row = chunk*16 + lane/4, k = (lane&3)*8.
// If Mptr != null, M is read from device (pruned-row launch); excess blocks
// exit before any barrier.
// ---------------------------------------------------------------------------
template<int ACT, bool OBF>
__global__ __launch_bounds__(256)
void gemm_nt128(const unsigned short* __restrict__ A,
                const unsigned short* __restrict__ B,
                const float* __restrict__ bias,
                void* __restrict__ Cv,
                int M, const int* __restrict__ Mptr,
                int N, int K)
{
    if (Mptr) M = *Mptr;
    const int bm = blockIdx.y * 128;
    if (bm >= M) return;
    const int bn = blockIdx.x * 128;
    constexpr int BK = 32;

    __shared__ __align__(16) unsigned short As[128 * BK];   // 8 KB
    __shared__ __align__(16) unsigned short Bs[128 * BK];   // 8 KB

    const int tid  = threadIdx.x;
    const int wave = tid >> 6;
    const int lane = tid & 63;
    const int wr = wave >> 1, wc = wave & 1;

    // staging addresses (global per-lane, LDS wave-uniform chunk base)
    const int c0 = wave * 2;
    const int sr = lane >> 2;            // row within 16-row chunk
    const int sc = (lane & 3) << 3;      // k offset 0/8/16/24

    int ra0 = bm + c0 * 16 + sr;         if (ra0 >= M) ra0 = M - 1;
    int ra1 = bm + (c0 + 1) * 16 + sr;   if (ra1 >= M) ra1 = M - 1;
    int rb0 = bn + c0 * 16 + sr;         if (rb0 >= N) rb0 = N - 1;
    int rb1 = bn + (c0 + 1) * 16 + sr;   if (rb1 >= N) rb1 = N - 1;

    const unsigned short* Ag0 = A + (size_t)ra0 * K + sc;
    const unsigned short* Ag1 = A + (size_t)ra1 * K + sc;
    const unsigned short* Bg0 = B + (size_t)rb0 * K + sc;
    const unsigned short* Bg1 = B + (size_t)rb1 * K + sc;
    unsigned short* Al0 = &As[c0 * 512];
    unsigned short* Al1 = &As[(c0 + 1) * 512];
    unsigned short* Bl0 = &Bs[c0 * 512];
    unsigned short* Bl1 = &Bs[(c0 + 1) * 512];

    // fragment read addresses (verified m89/m92 layout)
    const int fr = lane & 15;
    const int fk = (lane >> 4) << 3;
    const unsigned short* AsF = &As[(wr * 64 + fr) * BK + fk];
    const unsigned short* BsF = &Bs[(wc * 64 + fr) * BK + fk];

    f32x4 acc[4][4];
#pragma unroll
    for (int m = 0; m < 4; ++m)
#pragma unroll
        for (int n = 0; n < 4; ++n) acc[m][n] = (f32x4)0.0f;

    for (int k0 = 0; k0 < K; k0 += BK) {
        glds16(Ag0 + k0, Al0);
        glds16(Ag1 + k0, Al1);
        glds16(Bg0 + k0, Bl0);
        glds16(Bg1 + k0, Bl1);
        __syncthreads();   // compiler drains vmcnt before s_barrier
        bf16x8 a[4], b[4];
#pragma unroll
        for (int m = 0; m < 4; ++m) a[m] = *(const bf16x8*)(AsF + m * 16 * BK);
#pragma unroll
        for (int n = 0; n < 4; ++n) b[n] = *(const bf16x8*)(BsF + n * 16 * BK);
#pragma unroll
        for (int m = 0; m < 4; ++m)
#pragma unroll
            for (int n = 0; n < 4; ++n)
                acc[m][n] = __builtin_amdgcn_mfma_f32_16x16x32_bf16(a[m], b[n], acc[m][n], 0, 0, 0);
        __syncthreads();
    }

    // epilogue: C row = (lane>>4)*4 + r, col = lane&15 within each 16x16 frag
    const int rr = (lane >> 4) << 2;
    const int cc = lane & 15;
#pragma unroll
    for (int m = 0; m < 4; ++m) {
        const int row = bm + wr * 64 + m * 16 + rr;
#pragma unroll
        for (int n = 0; n < 4; ++n) {
            const int col = bn + wc * 64 + n * 16 + cc;
            if (col >= N) continue;
            const float bv = bias ? bias[col] : 0.0f;
#pragma unroll
            for (int r = 0; r < 4; ++r) {
                if (row + r < M) {
                    float v = acc[m][n][r] + bv;
                    if (ACT == 1) v = tanhf(v);
                    if (OBF) ((unsigned short*)Cv)[(size_t)(row + r) * N + col] = f2b(v);
                    else     ((float*)Cv)[(size_t)(row + r) * N + col] = v;
                }
            }
        }
    }
}

// gi0[j] = dot(enc, W_ih[j,:]) + b_ih[j]  (fp32 exact). One wave per output j.
__global__ void k_gi0(const float* __restrict__ enc,
                      const float* __restrict__ Wih,
                      const float* __restrict__ bih,
                      float* __restrict__ gi0)
{
    int j = blockIdx.x * 4 + (threadIdx.x >> 6);
    int lane = threadIdx.x & 63;
    if (j >= D3) return;
    const float* w = Wih + (size_t)j * D;
    float s = 0.0f;
    for (int k = lane; k < D; k += 64) s += enc[k] * w[k];
#pragma unroll
    for (int off = 32; off > 0; off >>= 1) s += __shfl_xor(s, off, 64);
    if (lane == 0) gi0[j] = s + bih[j];
}

// r0 = GRU(x=enc via gi0 row, h=sub) using gh = sub@Whh^T+bhh. r0 out bf16.
__global__ void k_r0(const float* __restrict__ gi0, const float* __restrict__ gh,
                     const unsigned short* __restrict__ sub,
                     unsigned short* __restrict__ r0, int S)
{
    int idx = blockIdx.x * blockDim.x + threadIdx.x;
    if (idx >= S * D) return;
    int s = idx / D, d = idx - s * D;
    const float* g = gh + (size_t)s * D3;
    float r = sigm(gi0[d] + g[d]);
    float z = sigm(gi0[D + d] + g[D + d]);
    float n = tanhf(gi0[2 * D + d] + r * g[2 * D + d]);
    float h = b2f(sub[idx]);
    r0[idx] = f2b((1.0f - z) * n + z * h);
}

// --- winner machinery (int-only; runs first so edge math can be pruned) ---
__global__ void k_seed_st(const int* __restrict__ se, int* __restrict__ seed_pos,
                          int* __restrict__ best, int S, int stride)
{
    int s = blockIdx.x * blockDim.x + threadIdx.x;
    if (s >= S) return;
    int node = se[s];
    atomicMax(&seed_pos[node], s);
    atomicMax(&best[node], s * stride);
}

__global__ void k_edge_time(const int* __restrict__ heads, const int* __restrict__ tails,
                            const int* __restrict__ seed_pos, int* __restrict__ best,
                            int E, int stride)
{
    int e = blockIdx.x * blockDim.x + threadIdx.x;
    if (e >= E) return;
    int p = seed_pos[heads[e]];
    int t = p * stride + 1 + e;
    if (t < 0) return;
    atomicMax(&best[tails[e]], t);
}

__global__ void k_seed_win(const int* __restrict__ se, const int* __restrict__ best,
                           int* __restrict__ winner, int S, int stride)
{
    int s = blockIdx.x * blockDim.x + threadIdx.x;
    if (s >= S) return;
    int node = se[s];
    if (best[node] == s * stride) winner[node] = s;
}

__global__ void k_edge_win(const int* __restrict__ heads, const int* __restrict__ tails,
                           const int* __restrict__ seed_pos, const int* __restrict__ best,
                           int* __restrict__ winner, int E, int S, int stride)
{
    int e = blockIdx.x * blockDim.x + threadIdx.x;
    if (e >= E) return;
    int p = seed_pos[heads[e]];
    int t = p * stride + 1 + e;
    if (t < 0) return;
    int node = tails[e];
    if (best[node] == t) winner[node] = S + e;
}

// compact winning edges: wedge[row] = edge id, objrow[node] = row
__global__ void k_compact(const int* __restrict__ best, const int* __restrict__ winner,
                          int* __restrict__ cnt, int* __restrict__ wedge,
                          int* __restrict__ objrow, int N, int S)
{
    int n = blockIdx.x * blockDim.x + threadIdx.x;
    if (n >= N) return;
    int w = winner[n];
    if (best[n] >= 0 && w >= S) {
        int r = atomicAdd(cnt, 1);
        wedge[r] = w - S;
        objrow[n] = r;
    }
}

// rj for WINNING edges only: one wave per compacted row, float4 gate loads.
__global__ void k_edge2(const int* __restrict__ wedge, const int* __restrict__ cntp,
                        const int* __restrict__ heads, const int* __restrict__ types,
                        const float* __restrict__ Gi, const float* __restrict__ Ghr,
                        const float* __restrict__ rel,
                        unsigned short* __restrict__ rjw)
{
    const int W = *cntp;
    const int wave = threadIdx.x >> 6;
    const int lane = threadIdx.x & 63;
    for (int row = blockIdx.x * 4 + wave; row < W; row += gridDim.x * 4) {
        int e = wedge[row];
        int hd = heads[e], t = types[e];
        const float* gi = Gi + (size_t)hd * D3;
        const float* gh = Ghr + (size_t)t * D3;
        const float* rl = rel + (size_t)t * D;
        unsigned short* out = rjw + (size_t)row * D;
#pragma unroll
        for (int i = 0; i < 3; ++i) {
            int d = i * 256 + lane * 4;
            float4 vr = *(const float4*)(gi + d);
            float4 hr = *(const float4*)(gh + d);
            float4 vz = *(const float4*)(gi + D + d);
            float4 hz = *(const float4*)(gh + D + d);
            float4 vn = *(const float4*)(gi + 2 * D + d);
            float4 hn = *(const float4*)(gh + 2 * D + d);
            float4 hh = *(const float4*)(rl + d);
            ushort4 o;
            { float r = sigm(vr.x + hr.x), z = sigm(vz.x + hz.x);
              float n = tanhf(vn.x + r * hn.x);
              o.x = f2b((1.0f - z) * n + z * hh.x); }
            { float r = sigm(vr.y + hr.y), z = sigm(vz.y + hz.y);
              float n = tanhf(vn.y + r * hn.y);
              o.y = f2b((1.0f - z) * n + z * hh.y); }
            { float r = sigm(vr.z + hr.z), z = sigm(vz.z + hz.z);
              float n = tanhf(vn.z + r * hn.z);
              o.z = f2b((1.0f - z) * n + z * hh.z); }
            { float r = sigm(vr.w + hr.w), z = sigm(vz.w + hz.w);
              float n = tanhf(vn.w + r * hn.w);
              o.w = f2b((1.0f - z) * n + z * hh.w); }
            *(ushort4*)(out + d) = o;
        }
    }
}

// out[i,:] (fp32) = written ? (winner<S ? sub[winner] : objw[objrow]) : default[i]
__global__ void k_out(const int* __restrict__ n2n, const int* __restrict__ oldnd,
                      const int* __restrict__ best, const int* __restrict__ winner,
                      const int* __restrict__ objrow,
                      const unsigned short* __restrict__ sub,
                      const unsigned short* __restrict__ obj,
                      const float* __restrict__ defnd,
                      float* __restrict__ out, int N, int S)
{
    int idx = blockIdx.x * blockDim.x + threadIdx.x;
    const int JP = D / 4;
    if (idx >= N * JP) return;
    int i = idx / JP, j = idx - i * JP;
    int id = n2n[oldnd[i]];
    float4 v;
    if (best[id] >= 0) {
        int w = winner[id];
        const unsigned short* src = (w < S) ? sub + (size_t)w * D + j * 4
                                            : obj + (size_t)objrow[id] * D + j * 4;
        ushort4 u = *(const ushort4*)src;
        v.x = b2f(u.x); v.y = b2f(u.y); v.z = b2f(u.z); v.w = b2f(u.w);
    } else {
        v = *(const float4*)(defnd + (size_t)i * D + j * 4);
    }
    *(float4*)(out + (size_t)i * D + j * 4) = v;
}

extern "C" void kernel_launch(void* const* d_in, const int* in_sizes, int n_in,
                              void* d_out, int out_size, void* d_ws, size_t ws_size,
                              hipStream_t stream)
{
    const float* enc    = (const float*)d_in[0];
    const float* smask  = (const float*)d_in[1];
    const int* seed_ent = (const int*)d_in[2];
    const int* eheads   = (const int*)d_in[3];
    const int* etails   = (const int*)d_in[4];
    const int* etype    = (const int*)d_in[5];
    const int* n2n      = (const int*)d_in[6];
    const int* oldnd    = (const int*)d_in[7];
    const float* rel    = (const float*)d_in[8];
    const float* Wsub   = (const float*)d_in[9];
    const float* bsub   = (const float*)d_in[10];
    const float* Wobj   = (const float*)d_in[11];
    const float* bobj   = (const float*)d_in[12];
    const float* Wih    = (const float*)d_in[13];
    const float* Whh    = (const float*)d_in[14];
    const float* bih    = (const float*)d_in[15];
    const float* bhh    = (const float*)d_in[16];
    const float* defnd  = (const float*)d_in[17];

    const int S = in_sizes[2];
    const int E = in_sizes[3];
    const int N = in_sizes[6];
    const int R = in_sizes[8] / D;
    const int stride = E + 1;
    const int maxW = (E < N) ? E : N;   // <=1 winning edge per node

    // workspace carve (256B aligned)
    char* p = (char*)d_ws;
    auto carve = [&](size_t bytes) -> char* {
        char* r = p; p += (bytes + 255) & ~(size_t)255; return r;
    };
    unsigned short* smask_b = (unsigned short*)carve((size_t)S * D * 2);
    unsigned short* Wsub_b  = (unsigned short*)carve((size_t)D * D * 2);
    unsigned short* Wobj_b  = (unsigned short*)carve((size_t)D * D * 2);
    unsigned short* Wih_b   = (unsigned short*)carve((size_t)D3 * D * 2);
    unsigned short* Whh_b   = (unsigned short*)carve((size_t)D3 * D * 2);
    unsigned short* rel_b   = (unsigned short*)carve((size_t)R * D * 2);
    unsigned short* sub     = (unsigned short*)carve((size_t)S * D * 2);
    unsigned short* r0      = (unsigned short*)carve((size_t)S * D * 2);
    unsigned short* rj      = (unsigned short*)carve((size_t)maxW * D * 2);
    unsigned short* obj     = (unsigned short*)carve((size_t)maxW * D * 2);
    float* gi0 = (float*)carve((size_t)D3 * 4);
    float* gh  = (float*)carve((size_t)S * D3 * 4);   // reused as Gi
    float* ghr = (float*)carve((size_t)R * D3 * 4);
    int* seed_pos = (int*)carve((size_t)N * 4);
    int* best     = (int*)carve((size_t)N * 4);
    int* winner   = (int*)carve((size_t)N * 4);
    int* wedge    = (int*)carve((size_t)maxW * 4);
    int* objrow   = (int*)carve((size_t)N * 4);
    int* cnt      = (int*)carve(256);

    dim3 blk(256);
    auto g1 = [](int n) { return dim3((n + 255) / 256); };
    auto gemmg = [](int M, int N_) { return dim3(N_ / 128, (M + 127) / 128); };

    hipMemsetAsync(seed_pos, 0xFF, (size_t)N * 4, stream);
    hipMemsetAsync(best,     0xFF, (size_t)N * 4, stream);
    hipMemsetAsync(winner,   0xFF, (size_t)N * 4, stream);
    hipMemsetAsync(cnt,      0x00, 4, stream);

    // ---- winner resolution first (int-only) -> prune edge embedding work ----
    k_seed_st  <<<g1(S), blk, 0, stream>>>(seed_ent, seed_pos, best, S, stride);
    k_edge_time<<<g1(E), blk, 0, stream>>>(eheads, etails, seed_pos, best, E, stride);
    k_seed_win <<<g1(S), blk, 0, stream>>>(seed_ent, best, winner, S, stride);
    k_edge_win <<<g1(E), blk, 0, stream>>>(eheads, etails, seed_pos, best, winner, E, S, stride);
    k_compact  <<<g1(N), blk, 0, stream>>>(best, winner, cnt, wedge, objrow, N, S);

    // ---- fp32 -> bf16 casts for GEMM operands ----
    k_cast<<<g1(S * D / 4),  blk, 0, stream>>>(smask, smask_b, S * D);
    k_cast<<<g1(D * D / 4),  blk, 0, stream>>>(Wsub,  Wsub_b,  D * D);
    k_cast<<<g1(D * D / 4),  blk, 0, stream>>>(Wobj,  Wobj_b,  D * D);
    k_cast<<<g1(D3 * D / 4), blk, 0, stream>>>(Wih,   Wih_b,   D3 * D);
    k_cast<<<g1(D3 * D / 4), blk, 0, stream>>>(Whh,   Whh_b,   D3 * D);
    k_cast<<<g1(R * D / 4),  blk, 0, stream>>>(rel,   rel_b,   R * D);

    // sub = tanh(smask @ Wsub^T + bsub)  [S,D] bf16
    gemm_nt128<1, true><<<gemmg(S, D), blk, 0, stream>>>(
        smask_b, Wsub_b, bsub, sub, S, nullptr, D, D);
    // gi0 row (fp32 exact)
    k_gi0<<<dim3((D3 + 3) / 4), blk, 0, stream>>>(enc, Wih, bih, gi0);
    // gh = sub @ Whh^T + bhh  [S,3D] f32
    gemm_nt128<0, false><<<gemmg(S, D3), blk, 0, stream>>>(
        sub, Whh_b, bhh, gh, S, nullptr, D3, D);
    // r0 combine -> bf16
    k_r0<<<g1(S * D), blk, 0, stream>>>(gi0, gh, sub, r0, S);
    // Gi = r0 @ Wih^T + bih  [S,3D] f32 (reuse gh buffer)
    gemm_nt128<0, false><<<gemmg(S, D3), blk, 0, stream>>>(
        r0, Wih_b, bih, gh, S, nullptr, D3, D);
    // Ghr = rel @ Whh^T + bhh  [R,3D] f32
    gemm_nt128<0, false><<<gemmg(R, D3), blk, 0, stream>>>(
        rel_b, Whh_b, bhh, ghr, R, nullptr, D3, D);

    // rj for winning edges only -> bf16 [W, D]
    k_edge2<<<dim3(2048), blk, 0, stream>>>(wedge, cnt, eheads, etype, gh, ghr, rel, rj);
    // obj = tanh(rj @ Wobj^T + bobj)  [W, D] bf16 (M read from device counter)
    gemm_nt128<1, true><<<gemmg(maxW, D), blk, 0, stream>>>(
        rj, Wobj_b, bobj, obj, maxW, cnt, D, D);

    // output (fp32)
    k_out<<<g1(N * (D / 4)), blk, 0, stream>>>(
        n2n, oldnd, best, winner, objrow, sub, obj, defnd, (float*)d_out, N, S);
}

// Round 2
// 867.064 us; speedup vs baseline: 1.0494x; 1.0494x over previous
//
#include <hip/hip_runtime.h>

#define D 768
#define D3 2304

typedef __bf16 bf16x8 __attribute__((ext_vector_type(8)));
typedef float f32x4 __attribute__((ext_vector_type(4)));

__device__ __forceinline__ float b2f(unsigned short u) {
    unsigned int i = ((unsigned int)u) << 16;
    return __builtin_bit_cast(float, i);
}
__device__ __forceinline__ unsigned short f2b(float f) {
    unsigned int i = __builtin_bit_cast(unsigned int, f);
    i += 0x7FFFu + ((i >> 16) & 1u);   // RNE
    return (unsigned short)(i >> 16);
}
__device__ __forceinline__ float sigm(float x) { return 1.0f / (1.0f + __expf(-x)); }

// async global->LDS, 16B per lane. LDS dest is wave-uniform base + lane*16.
typedef __attribute__((address_space(1))) const unsigned int* as1p;
typedef __attribute__((address_space(3))) unsigned int* as3p;
__device__ __forceinline__ void glds16(const unsigned short* g, unsigned short* l)
{
    __builtin_amdgcn_global_load_lds((as1p)g, (as3p)l, 16, 0, 0);
}

// fused fp32 -> bf16 cast over 6 segments (4 elems/thread)
__global__ void k_cast6(const float* __restrict__ s0, const float* __restrict__ s1,
                        const float* __restrict__ s2, const float* __restrict__ s3,
                        const float* __restrict__ s4, const float* __restrict__ s5,
                        unsigned short* __restrict__ d0, unsigned short* __restrict__ d1,
                        unsigned short* __restrict__ d2, unsigned short* __restrict__ d3,
                        unsigned short* __restrict__ d4, unsigned short* __restrict__ d5,
                        int c0, int c1, int c2, int c3, int c4, int c5)
{
    int g = blockIdx.x * blockDim.x + threadIdx.x;
    const float* src; unsigned short* dst; int base;
    if      (g < c0) { src = s0; dst = d0; base = 0;  }
    else if (g < c1) { src = s1; dst = d1; base = c0; }
    else if (g < c2) { src = s2; dst = d2; base = c1; }
    else if (g < c3) { src = s3; dst = d3; base = c2; }
    else if (g < c4) { src = s4; dst = d4; base = c3; }
    else if (g < c5) { src = s5; dst = d5; base = c4; }
    else return;
    int i4 = (g - base) * 4;
    float4 v = *(const float4*)(src + i4);
    ushort4 u;
    u.x = f2b(v.x); u.y = f2b(v.y); u.z = f2b(v.z); u.w = f2b(v.w);
    *(ushort4*)(dst + i4) = u;
}

// ---------------------------------------------------------------------------
// NT GEMM, m97 structure: C[M,N] = act(A[M,K] @ B[N,K]^T + bias[N])
// 128x128 tile, BK=32, 4 waves (2x2), 4x4 16x16x32 MFMA frags per wave.
// Staging via global_load_lds width=16. If Mptr != null, M is read from
// device (pruned-row launch); excess blocks exit before any barrier.
// ---------------------------------------------------------------------------
template<int ACT, bool OBF>
__global__ __launch_bounds__(256)
void gemm_nt128(const unsigned short* __restrict__ A,
                const unsigned short* __restrict__ B,
                const float* __restrict__ bias,
                void* __restrict__ Cv,
                int M, const int* __restrict__ Mptr,
                int N, int K)
{
    if (Mptr) M = *Mptr;
    const int bm = blockIdx.y * 128;
    if (bm >= M) return;
    const int bn = blockIdx.x * 128;
    constexpr int BK = 32;

    __shared__ __align__(16) unsigned short As[128 * BK];   // 8 KB
    __shared__ __align__(16) unsigned short Bs[128 * BK];   // 8 KB

    const int tid  = threadIdx.x;
    const int wave = tid >> 6;
    const int lane = tid & 63;
    const int wr = wave >> 1, wc = wave & 1;

    const int c0 = wave * 2;
    const int sr = lane >> 2;            // row within 16-row chunk
    const int sc = (lane & 3) << 3;      // k offset 0/8/16/24

    int ra0 = bm + c0 * 16 + sr;         if (ra0 >= M) ra0 = M - 1;
    int ra1 = bm + (c0 + 1) * 16 + sr;   if (ra1 >= M) ra1 = M - 1;
    int rb0 = bn + c0 * 16 + sr;         if (rb0 >= N) rb0 = N - 1;
    int rb1 = bn + (c0 + 1) * 16 + sr;   if (rb1 >= N) rb1 = N - 1;

    const unsigned short* Ag0 = A + (size_t)ra0 * K + sc;
    const unsigned short* Ag1 = A + (size_t)ra1 * K + sc;
    const unsigned short* Bg0 = B + (size_t)rb0 * K + sc;
    const unsigned short* Bg1 = B + (size_t)rb1 * K + sc;
    unsigned short* Al0 = &As[c0 * 512];
    unsigned short* Al1 = &As[(c0 + 1) * 512];
    unsigned short* Bl0 = &Bs[c0 * 512];
    unsigned short* Bl1 = &Bs[(c0 + 1) * 512];

    const int fr = lane & 15;
    const int fk = (lane >> 4) << 3;
    const unsigned short* AsF = &As[(wr * 64 + fr) * BK + fk];
    const unsigned short* BsF = &Bs[(wc * 64 + fr) * BK + fk];

    f32x4 acc[4][4];
#pragma unroll
    for (int m = 0; m < 4; ++m)
#pragma unroll
        for (int n = 0; n < 4; ++n) acc[m][n] = (f32x4)0.0f;

    for (int k0 = 0; k0 < K; k0 += BK) {
        glds16(Ag0 + k0, Al0);
        glds16(Ag1 + k0, Al1);
        glds16(Bg0 + k0, Bl0);
        glds16(Bg1 + k0, Bl1);
        __syncthreads();
        bf16x8 a[4], b[4];
#pragma unroll
        for (int m = 0; m < 4; ++m) a[m] = *(const bf16x8*)(AsF + m * 16 * BK);
#pragma unroll
        for (int n = 0; n < 4; ++n) b[n] = *(const bf16x8*)(BsF + n * 16 * BK);
#pragma unroll
        for (int m = 0; m < 4; ++m)
#pragma unroll
            for (int n = 0; n < 4; ++n)
                acc[m][n] = __builtin_amdgcn_mfma_f32_16x16x32_bf16(a[m], b[n], acc[m][n], 0, 0, 0);
        __syncthreads();
    }

    const int rr = (lane >> 4) << 2;
    const int cc = lane & 15;
#pragma unroll
    for (int m = 0; m < 4; ++m) {
        const int row = bm + wr * 64 + m * 16 + rr;
#pragma unroll
        for (int n = 0; n < 4; ++n) {
            const int col = bn + wc * 64 + n * 16 + cc;
            if (col >= N) continue;
            const float bv = bias ? bias[col] : 0.0f;
#pragma unroll
            for (int r = 0; r < 4; ++r) {
                if (row + r < M) {
                    float v = acc[m][n][r] + bv;
                    if (ACT == 1) v = tanhf(v);
                    if (OBF) ((unsigned short*)Cv)[(size_t)(row + r) * N + col] = f2b(v);
                    else     ((float*)Cv)[(size_t)(row + r) * N + col] = v;
                }
            }
        }
    }
}

// gi0[j] = dot(enc, W_ih[j,:]) + b_ih[j]  (fp32 exact). One wave per output j.
__global__ void k_gi0(const float* __restrict__ enc,
                      const float* __restrict__ Wih,
                      const float* __restrict__ bih,
                      float* __restrict__ gi0)
{
    int j = blockIdx.x * 4 + (threadIdx.x >> 6);
    int lane = threadIdx.x & 63;
    if (j >= D3) return;
    const float* w = Wih + (size_t)j * D;
    float s = 0.0f;
    for (int k = lane; k < D; k += 64) s += enc[k] * w[k];
#pragma unroll
    for (int off = 32; off > 0; off >>= 1) s += __shfl_xor(s, off, 64);
    if (lane == 0) gi0[j] = s + bih[j];
}

// r0 = GRU(x=enc via gi0 row, h=sub) using gh = sub@Whh^T+bhh. r0 out bf16.
__global__ void k_r0(const float* __restrict__ gi0, const float* __restrict__ gh,
                     const unsigned short* __restrict__ sub,
                     unsigned short* __restrict__ r0, int S)
{
    int idx = blockIdx.x * blockDim.x + threadIdx.x;
    if (idx >= S * D) return;
    int s = idx / D, d = idx - s * D;
    const float* g = gh + (size_t)s * D3;
    float r = sigm(gi0[d] + g[d]);
    float z = sigm(gi0[D + d] + g[D + d]);
    float n = tanhf(gi0[2 * D + d] + r * g[2 * D + d]);
    float h = b2f(sub[idx]);
    r0[idx] = f2b((1.0f - z) * n + z * h);
}

// --- winner machinery (int-only; runs first so edge math can be pruned) ---
__global__ void k_seed_st(const int* __restrict__ se, int* __restrict__ seed_pos,
                          int* __restrict__ best, int S, int stride)
{
    int s = blockIdx.x * blockDim.x + threadIdx.x;
    if (s >= S) return;
    int node = se[s];
    atomicMax(&seed_pos[node], s);
    atomicMax(&best[node], s * stride);
}

__global__ void k_edge_time(const int* __restrict__ heads, const int* __restrict__ tails,
                            const int* __restrict__ seed_pos, int* __restrict__ best,
                            int E, int stride)
{
    int e = blockIdx.x * blockDim.x + threadIdx.x;
    if (e >= E) return;
    int p = seed_pos[heads[e]];
    int t = p * stride + 1 + e;
    if (t < 0) return;
    atomicMax(&best[tails[e]], t);
}

// seed winners -> winner[]; edge winners -> per-type histogram
__global__ void k_win(const int* __restrict__ se,
                      const int* __restrict__ heads, const int* __restrict__ tails,
                      const int* __restrict__ types,
                      const int* __restrict__ seed_pos, const int* __restrict__ best,
                      int* __restrict__ winner, int* __restrict__ thist,
                      int S, int E, int stride)
{
    int idx = blockIdx.x * blockDim.x + threadIdx.x;
    if (idx < S) {
        int node = se[idx];
        if (best[node] == idx * stride) winner[node] = idx;
    } else {
        int e = idx - S;
        if (e >= E) return;
        int p = seed_pos[heads[e]];
        int t = p * stride + 1 + e;
        if (t < 0) return;
        if (best[tails[e]] == t) atomicAdd(&thist[types[e]], 1);
    }
}

// exclusive scan of thist[R] -> toff[R]; total -> *cnt. Single 256-thread block.
__global__ void k_scan(const int* __restrict__ thist, int* __restrict__ toff,
                       int* __restrict__ cnt, int R)
{
    __shared__ int wsum[4];
    __shared__ int chunkbase;
    const int tid  = threadIdx.x;
    const int lane = tid & 63;
    const int wave = tid >> 6;
    if (tid == 0) chunkbase = 0;
    __syncthreads();
    for (int base0 = 0; base0 < R; base0 += 1024) {
        int v[4]; int s = 0;
        int base = base0 + tid * 4;
#pragma unroll
        for (int j = 0; j < 4; ++j) {
            int i = base + j;
            v[j] = (i < R) ? thist[i] : 0;
            s += v[j];
        }
        int tsum = s;
#pragma unroll
        for (int off = 1; off < 64; off <<= 1) {
            int o = __shfl_up(tsum, off, 64);
            if (lane >= off) tsum += o;
        }
        if (lane == 63) wsum[wave] = tsum;
        __syncthreads();
        int wbase = 0;
        for (int w = 0; w < 4; ++w) if (w < wave) wbase += wsum[w];
        int run = chunkbase + wbase + (tsum - s);   // exclusive prefix
#pragma unroll
        for (int j = 0; j < 4; ++j) {
            int i = base + j;
            if (i < R) toff[i] = run;
            run += v[j];
        }
        __syncthreads();
        if (tid == 0) chunkbase += wsum[0] + wsum[1] + wsum[2] + wsum[3];
        __syncthreads();
    }
    if (tid == 0) *cnt = chunkbase;
}

// scatter winning edges into type-sorted compact rows
__global__ void k_scatter(const int* __restrict__ heads, const int* __restrict__ tails,
                          const int* __restrict__ types,
                          const int* __restrict__ seed_pos, const int* __restrict__ best,
                          const int* __restrict__ toff, int* __restrict__ tcur,
                          int* __restrict__ wedge, int* __restrict__ objrow,
                          int E, int stride)
{
    int e = blockIdx.x * blockDim.x + threadIdx.x;
    if (e >= E) return;
    int p = seed_pos[heads[e]];
    int t = p * stride + 1 + e;
    if (t < 0) return;
    int node = tails[e];
    if (best[node] != t) return;
    int ty = types[e];
    int r = toff[ty] + atomicAdd(&tcur[ty], 1);
    wedge[r] = e;
    objrow[node] = r;
}

// rj for WINNING edges only (type-sorted): one wave per row, float4 gate loads.
__global__ void k_edge2(const int* __restrict__ wedge, const int* __restrict__ cntp,
                        const int* __restrict__ heads, const int* __restrict__ types,
                        const float* __restrict__ Gi, const float* __restrict__ Ghr,
                        const float* __restrict__ rel,
                        unsigned short* __restrict__ rjw)
{
    const int W = *cntp;
    const int wave = threadIdx.x >> 6;
    const int lane = threadIdx.x & 63;
    for (int row = blockIdx.x * 4 + wave; row < W; row += gridDim.x * 4) {
        int e = wedge[row];
        int hd = heads[e], t = types[e];
        const float* gi = Gi + (size_t)hd * D3;
        const float* gh = Ghr + (size_t)t * D3;
        const float* rl = rel + (size_t)t * D;
        unsigned short* out = rjw + (size_t)row * D;
#pragma unroll
        for (int i = 0; i < 3; ++i) {
            int d = i * 256 + lane * 4;
            float4 vr = *(const float4*)(gi + d);
            float4 hr = *(const float4*)(gh + d);
            float4 vz = *(const float4*)(gi + D + d);
            float4 hz = *(const float4*)(gh + D + d);
            float4 vn = *(const float4*)(gi + 2 * D + d);
            float4 hn = *(const float4*)(gh + 2 * D + d);
            float4 hh = *(const float4*)(rl + d);
            ushort4 o;
            { float r = sigm(vr.x + hr.x), z = sigm(vz.x + hz.x);
              float n = tanhf(vn.x + r * hn.x);
              o.x = f2b((1.0f - z) * n + z * hh.x); }
            { float r = sigm(vr.y + hr.y), z = sigm(vz.y + hz.y);
              float n = tanhf(vn.y + r * hn.y);
              o.y = f2b((1.0f - z) * n + z * hh.y); }
            { float r = sigm(vr.z + hr.z), z = sigm(vz.z + hz.z);
              float n = tanhf(vn.z + r * hn.z);
              o.z = f2b((1.0f - z) * n + z * hh.z); }
            { float r = sigm(vr.w + hr.w), z = sigm(vz.w + hz.w);
              float n = tanhf(vn.w + r * hn.w);
              o.w = f2b((1.0f - z) * n + z * hh.w); }
            *(ushort4*)(out + d) = o;
        }
    }
}

// out[i,:] (fp32) = written ? (objrow>=0 ? obj[objrow] : sub[winner]) : default[i]
__global__ void k_out(const int* __restrict__ n2n, const int* __restrict__ oldnd,
                      const int* __restrict__ best, const int* __restrict__ winner,
                      const int* __restrict__ objrow,
                      const unsigned short* __restrict__ sub,
                      const unsigned short* __restrict__ obj,
                      const float* __restrict__ defnd,
                      float* __restrict__ out, int N, int S)
{
    int idx = blockIdx.x * blockDim.x + threadIdx.x;
    const int JP = D / 4;
    if (idx >= N * JP) return;
    int i = idx / JP, j = idx - i * JP;
    int id = n2n[oldnd[i]];
    float4 v;
    if (best[id] >= 0) {
        int orow = objrow[id];
        const unsigned short* src = (orow >= 0) ? obj + (size_t)orow * D + j * 4
                                                : sub + (size_t)winner[id] * D + j * 4;
        ushort4 u = *(const ushort4*)src;
        v.x = b2f(u.x); v.y = b2f(u.y); v.z = b2f(u.z); v.w = b2f(u.w);
    } else {
        v = *(const float4*)(defnd + (size_t)i * D + j * 4);
    }
    *(float4*)(out + (size_t)i * D + j * 4) = v;
}

extern "C" void kernel_launch(void* const* d_in, const int* in_sizes, int n_in,
                              void* d_out, int out_size, void* d_ws, size_t ws_size,
                              hipStream_t stream)
{
    const float* enc    = (const float*)d_in[0];
    const float* smask  = (const float*)d_in[1];
    const int* seed_ent = (const int*)d_in[2];
    const int* eheads   = (const int*)d_in[3];
    const int* etails   = (const int*)d_in[4];
    const int* etype    = (const int*)d_in[5];
    const int* n2n      = (const int*)d_in[6];
    const int* oldnd    = (const int*)d_in[7];
    const float* rel    = (const float*)d_in[8];
    const float* Wsub   = (const float*)d_in[9];
    const float* bsub   = (const float*)d_in[10];
    const float* Wobj   = (const float*)d_in[11];
    const float* bobj   = (const float*)d_in[12];
    const float* Wih    = (const float*)d_in[13];
    const float* Whh    = (const float*)d_in[14];
    const float* bih    = (const float*)d_in[15];
    const float* bhh    = (const float*)d_in[16];
    const float* defnd  = (const float*)d_in[17];

    const int S = in_sizes[2];
    const int E = in_sizes[3];
    const int N = in_sizes[6];
    const int R = in_sizes[8] / D;
    const int stride = E + 1;
    const int maxW = (E < N) ? E : N;   // <=1 winning edge per node

    // workspace carve (256B aligned)
    char* p = (char*)d_ws;
    auto carve = [&](size_t bytes) -> char* {
        char* r = p; p += (bytes + 255) & ~(size_t)255; return r;
    };
    unsigned short* smask_b = (unsigned short*)carve((size_t)S * D * 2);
    unsigned short* Wsub_b  = (unsigned short*)carve((size_t)D * D * 2);
    unsigned short* Wobj_b  = (unsigned short*)carve((size_t)D * D * 2);
    unsigned short* Wih_b   = (unsigned short*)carve((size_t)D3 * D * 2);
    unsigned short* Whh_b   = (unsigned short*)carve((size_t)D3 * D * 2);
    unsigned short* rel_b   = (unsigned short*)carve((size_t)R * D * 2);
    unsigned short* sub     = (unsigned short*)carve((size_t)S * D * 2);
    unsigned short* r0      = (unsigned short*)carve((size_t)S * D * 2);
    unsigned short* rj      = (unsigned short*)carve((size_t)maxW * D * 2);
    unsigned short* obj     = (unsigned short*)carve((size_t)maxW * D * 2);
    float* gi0 = (float*)carve((size_t)D3 * 4);
    float* gh  = (float*)carve((size_t)S * D3 * 4);   // reused as Gi
    float* ghr = (float*)carve((size_t)R * D3 * 4);
    // 4 contiguous N-int arrays -> one 0xFF memset
    int* ints4    = (int*)carve((size_t)4 * N * 4);
    int* seed_pos = ints4;
    int* best     = ints4 + N;
    int* winner   = ints4 + 2 * (size_t)N;
    int* objrow   = ints4 + 3 * (size_t)N;
    // contiguous zeroed block: thist[R], tcur[R], toff[R], cnt
    int* zblk  = (int*)carve(((size_t)3 * R + 64) * 4);
    int* thist = zblk;
    int* tcur  = zblk + R;
    int* toff  = zblk + 2 * (size_t)R;
    int* cnt   = zblk + 3 * (size_t)R;
    int* wedge = (int*)carve((size_t)maxW * 4);

    dim3 blk(256);
    auto g1 = [](int n) { return dim3((n + 255) / 256); };
    auto gemmg = [](int M, int N_) { return dim3(N_ / 128, (M + 127) / 128); };

    hipMemsetAsync(ints4, 0xFF, (size_t)4 * N * 4, stream);
    hipMemsetAsync(zblk,  0x00, ((size_t)3 * R + 64) * 4, stream);

    // ---- fused fp32 -> bf16 casts ----
    const int gc0 = S * D / 4;
    const int gc1 = gc0 + D * D / 4;
    const int gc2 = gc1 + D * D / 4;
    const int gc3 = gc2 + D3 * D / 4;
    const int gc4 = gc3 + D3 * D / 4;
    const int gc5 = gc4 + R * D / 4;
    k_cast6<<<g1(gc5), blk, 0, stream>>>(smask, Wsub, Wobj, Wih, Whh, rel,
                                         smask_b, Wsub_b, Wobj_b, Wih_b, Whh_b, rel_b,
                                         gc0, gc1, gc2, gc3, gc4, gc5);

    // ---- winner resolution (int-only) with type-sorted compaction ----
    k_seed_st  <<<g1(S), blk, 0, stream>>>(seed_ent, seed_pos, best, S, stride);
    k_edge_time<<<g1(E), blk, 0, stream>>>(eheads, etails, seed_pos, best, E, stride);
    k_win      <<<g1(S + E), blk, 0, stream>>>(seed_ent, eheads, etails, etype,
                                               seed_pos, best, winner, thist, S, E, stride);
    k_scan     <<<dim3(1), blk, 0, stream>>>(thist, toff, cnt, R);
    k_scatter  <<<g1(E), blk, 0, stream>>>(eheads, etails, etype, seed_pos, best,
                                           toff, tcur, wedge, objrow, E, stride);

    // sub = tanh(smask @ Wsub^T + bsub)  [S,D] bf16
    gemm_nt128<1, true><<<gemmg(S, D), blk, 0, stream>>>(
        smask_b, Wsub_b, bsub, sub, S, nullptr, D, D);
    // gi0 row (fp32 exact)
    k_gi0<<<dim3((D3 + 3) / 4), blk, 0, stream>>>(enc, Wih, bih, gi0);
    // gh = sub @ Whh^T + bhh  [S,3D] f32
    gemm_nt128<0, false><<<gemmg(S, D3), blk, 0, stream>>>(
        sub, Whh_b, bhh, gh, S, nullptr, D3, D);
    // r0 combine -> bf16
    k_r0<<<g1(S * D), blk, 0, stream>>>(gi0, gh, sub, r0, S);
    // Gi = r0 @ Wih^T + bih  [S,3D] f32 (reuse gh buffer)
    gemm_nt128<0, false><<<gemmg(S, D3), blk, 0, stream>>>(
        r0, Wih_b, bih, gh, S, nullptr, D3, D);
    // Ghr = rel @ Whh^T + bhh  [R,3D] f32
    gemm_nt128<0, false><<<gemmg(R, D3), blk, 0, stream>>>(
        rel_b, Whh_b, bhh, ghr, R, nullptr, D3, D);

    // rj for winning edges (type-sorted) -> bf16 [W, D]
    k_edge2<<<dim3(2048), blk, 0, stream>>>(wedge, cnt, eheads, etype, gh, ghr, rel, rj);
    // obj = tanh(rj @ Wobj^T + bobj)  [W, D] bf16 (M read from device counter)
    gemm_nt128<1, true><<<gemmg(maxW, D), blk, 0, stream>>>(
        rj, Wobj_b, bobj, obj, maxW, cnt, D, D);

    // output (fp32)
    k_out<<<g1(N * (D / 4)), blk, 0, stream>>>(
        n2n, oldnd, best, winner, objrow, sub, obj, defnd, (float*)d_out, N, S);
}